// Round 12
// baseline (372.311 us; speedup 1.0000x reference)
//
#include <hip/hip_runtime.h>

// Problem constants (match reference)
constexpr int NN   = 50000;          // nodes
constexpr int NE   = 800000;         // edges before self loops
constexpr int NHD  = 4;              // heads
constexpr int CC   = 32;             // channels per head
constexpr int HCC  = 128;            // NHD*CC
constexpr int NL   = 3;              // layers
constexpr int NG   = 128;            // graphs
constexpr int NOUT = 10;             // out channels
constexpr float BN_EPS = 1e-5f;

constexpr int X2S = 67;              // LDS x-row stride in packed uints (bank-safe)
constexpr int YS = 33;               // LDS y-row stride
constexpr int NSLOT = 64;            // stats slots (atomic-contention spreading)
constexpr int NBUK = (NN + 127) / 128;    // 391 dst buckets (128 dsts each)
constexpr int EB  = 2048;            // edges per hist/bin block (391 blocks)
constexpr int EMB_BLKS = 512;        // embed-part blocks in k_pre

// NOTE (r10): cooperative mega-kernel with grid.sync() is 2.4x SLOWER on
// MI355X — grid.sync's device-scope coherence flushes the 8 non-coherent
// XCD L2s every phase (412MB HBM traffic). Do not retry.
// r8 instrumentation: kernels ~155us of baseline; rest is launch/fill overhead.
// r12: k_fused 512-thread (12->24 waves/CU), k_agg shuffle exp-dedup.

typedef __attribute__((ext_vector_type(2))) float f32x2;

// fp32 -> bf16 (round-to-nearest-even), packed pair helpers
__device__ inline unsigned f2bf_pack(float a, float b) {
    unsigned ua = __float_as_uint(a); ua += 0x7FFFu + ((ua >> 16) & 1u);
    unsigned ub = __float_as_uint(b); ub += 0x7FFFu + ((ub >> 16) & 1u);
    return (ua >> 16) | (ub & 0xFFFF0000u);
}
__device__ inline float bf_lo(unsigned p) { return __uint_as_float(p << 16); }
__device__ inline float bf_hi(unsigned p) { return __uint_as_float(p & 0xFFFF0000u); }
__device__ inline f32x2 bfpair(unsigned p) {
    f32x2 r; r.x = __uint_as_float(p << 16); r.y = __uint_as_float(p & 0xFFFF0000u);
    return r;
}

// ------------- k_pre: embed gather + BN stats (blocks 0..511)  merged with
//               CSR bucket histogram + per-graph counts (blocks 512..902)
__global__ __launch_bounds__(256) void k_pre(const int* __restrict__ idx,
                                             const float* __restrict__ embed,
                                             unsigned* __restrict__ xp,   // [N,64]
                                             float* __restrict__ stats,   // [64][256]
                                             const int* __restrict__ ei,
                                             int* __restrict__ bkcnt,
                                             const int* __restrict__ batch,
                                             float* __restrict__ gcnt) {
    int tid = threadIdx.x;
    if (blockIdx.x < EMB_BLKS) {
        __shared__ float A[256], B[256], C[256], D[256];
        int i0 = blockIdx.x * 256 + tid;
        int stride = EMB_BLKS * 256;
        float s0 = 0.f, s1 = 0.f, q0 = 0.f, q1 = 0.f;
        for (int i = i0; i < NN * 64; i += stride) {  // packed uints: 2 ch each
            int n = i >> 6, c2 = (i & 63) << 1;
            float2 ev = *(const float2*)(embed + (size_t)idx[n] * HCC + c2);
            xp[i] = f2bf_pack(ev.x, ev.y);
            s0 += ev.x; q0 += ev.x * ev.x;
            s1 += ev.y; q1 += ev.y * ev.y;
        }
        A[tid] = s0; B[tid] = s1; C[tid] = q0; D[tid] = q1;
        __syncthreads();
        int slot = blockIdx.x & (NSLOT - 1);
        if (tid < 64) {
            int p = tid;                              // channel pair (2p, 2p+1)
            float S0 = A[p] + A[p + 64] + A[p + 128] + A[p + 192];
            float S1 = B[p] + B[p + 64] + B[p + 128] + B[p + 192];
            float Q0 = C[p] + C[p + 64] + C[p + 128] + C[p + 192];
            float Q1 = D[p] + D[p + 64] + D[p + 128] + D[p + 192];
            atomicAdd(&stats[slot * 256 + 2 * p],           S0);
            atomicAdd(&stats[slot * 256 + 2 * p + 1],       S1);
            atomicAdd(&stats[slot * 256 + HCC + 2 * p],     Q0);
            atomicAdd(&stats[slot * 256 + HCC + 2 * p + 1], Q1);
        }
    } else {
        __shared__ int hist[NBUK];
        __shared__ int lgc[NG];
        int b = blockIdx.x - EMB_BLKS;
        int e0 = b * EB, nE = min(EB, NE - e0);
        for (int i = tid; i < NBUK; i += 256) hist[i] = 0;
        for (int i = tid; i < NG; i += 256) lgc[i] = 0;
        __syncthreads();
        for (int i = tid; i < nE; i += 256)
            atomicAdd(&hist[ei[NE + e0 + i] >> 7], 1);
        int n0 = b * 128;
        if (tid < 128) {
            int n = n0 + tid;
            if (n < NN) atomicAdd(&lgc[batch[n]], 1);
        }
        __syncthreads();
        for (int i = tid; i < NBUK; i += 256)
            if (hist[i]) atomicAdd(&bkcnt[i], hist[i]);
        for (int i = tid; i < NG; i += 256)
            if (lgc[i]) atomicAdd(&gcnt[i], (float)lgc[i]);
    }
}

// -------- CSR build 2: parallel exclusive scan of 391 bucket totals
__global__ __launch_bounds__(512) void k_bscan(const int* __restrict__ bkcnt,
                                               int* __restrict__ bbase,
                                               int* __restrict__ bcnt,
                                               int* __restrict__ rowptr) {
    __shared__ int sc[512];
    int t = threadIdx.x;
    int v = (t < NBUK) ? bkcnt[t] : 0;
    sc[t] = v;
    __syncthreads();
#pragma unroll
    for (int off = 1; off < 512; off <<= 1) {
        int u = (t >= off) ? sc[t - off] : 0;
        __syncthreads();
        sc[t] += u;
        __syncthreads();
    }
    if (t < NBUK) {
        int excl = sc[t] - v;
        bbase[t] = excl;
        bcnt[t]  = excl;                          // atomic tail counters for k_bin
    }
    if (t == 0) rowptr[NN] = NE;
}

// -------- CSR build 3: LDS-aggregated bucket binning (range-reserved).
__global__ __launch_bounds__(256) void k_bin(const int* __restrict__ ei,
                                             int* __restrict__ bcnt,
                                             unsigned* __restrict__ e_src) {
    __shared__ int hist[NBUK], base[NBUK];
    int b = blockIdx.x, t = threadIdx.x;
    int e0 = b * EB;
    int nE = min(EB, NE - e0);

    for (int i = t; i < NBUK; i += 256) hist[i] = 0;
    __syncthreads();
    for (int i = t; i < nE; i += 256)
        atomicAdd(&hist[ei[NE + e0 + i] >> 7], 1);
    __syncthreads();
    for (int i = t; i < NBUK; i += 256) {
        int c = hist[i];
        if (c) base[i] = atomicAdd(&bcnt[i], c);
        hist[i] = 0;                              // reuse as placement offset
    }
    __syncthreads();
    for (int i = t; i < nE; i += 256) {
        int e = e0 + i;
        int d = ei[NE + e];
        int s = ei[e];
        int bk = d >> 7;
        int pos = base[bk] + atomicAdd(&hist[bk], 1);
        e_src[pos] = (unsigned)s | ((unsigned)(d & 127) << 17);
    }
}

// -------- CSR build 4: within-bucket placement; derives per-node rowptr.
__global__ __launch_bounds__(512) void k_place(const int* __restrict__ bbase,
                                               unsigned* __restrict__ e_src,
                                               int* __restrict__ rowptr) {
    __shared__ int lcnt[128], sc[128], lrp[128], cnt[128];
    int b = blockIdx.x, t = threadIdx.x;
    int d0 = b * 128;
    int rS = bbase[b];
    int rE = (b + 1 < NBUK) ? bbase[b + 1] : NE;
    int n = rE - rS;
    if (t < 128) { lcnt[t] = 0; cnt[t] = 0; }
    __syncthreads();
    unsigned pk[7];
#pragma unroll
    for (int k = 0; k < 7; k++) {
        int i = t + k * 512;
        if (i < n) {
            pk[k] = e_src[rS + i];
            atomicAdd(&lcnt[pk[k] >> 17], 1);
        }
    }
    __syncthreads();
    if (t < 128) sc[t] = lcnt[t];
    __syncthreads();
#pragma unroll
    for (int off = 1; off < 128; off <<= 1) {
        int u = (t < 128 && t >= off) ? sc[t - off] : 0;
        __syncthreads();
        if (t < 128) sc[t] += u;
        __syncthreads();
    }
    if (t < 128) {
        int start = rS + sc[t] - lcnt[t];
        lrp[t] = start;
        int d = d0 + t;
        if (d < NN) rowptr[d] = start;
    }
    __syncthreads();
#pragma unroll
    for (int k = 0; k < 7; k++) {
        int i = t + k * 512;
        if (i < n) {
            unsigned p = pk[k];
            int dl = p >> 17;
            int pos = lrp[dl] + atomicAdd(&cnt[dl], 1);
            e_src[pos] = p & 0x1FFFFu;
        }
    }
}

// ---------- fused BNfin + BN-apply + Linear+ReLU + GATw + att dots
// r12: 512 threads / 8 waves per 64-node tile -> 24 waves/CU (was 12).
// stage1: 4 y-outputs per wave; stage2: 16 h-channels per wave (2 waves/head,
// partial head-dots combined via LDS).
__global__ __launch_bounds__(512) void k_fused(const unsigned* __restrict__ xp,
                                               const float* __restrict__ stats, // [64][256]
                                               const float* __restrict__ gamma,
                                               const float* __restrict__ beta,
                                               const float* __restrict__ W1, // [32,128]
                                               const float* __restrict__ b1, // [32]
                                               const float* __restrict__ W2, // [128,32]
                                               const float* __restrict__ aS, // [4,32]
                                               const float* __restrict__ aD, // [4,32]
                                               unsigned* __restrict__ h,     // [N,64] packed
                                               float* __restrict__ asrc,     // [N,4]
                                               float* __restrict__ adst) {   // [N,4]
    __shared__ unsigned xb2[64 * X2S];            // 17152 B
    __shared__ float yt[64 * YS];                 //  8448 B
    __shared__ float __attribute__((aligned(16))) ssl[256];
    __shared__ float sdS[8][64], sdD[8][64];      //  4096 B  (total 30720 B)
    int tid = threadIdx.x;
    int node0 = blockIdx.x * 64;
    int nNodes = min(64, NN - node0);

    // BN finalize: 512 threads, each sums half a stats column (yt as scratch)
    {
        int col = tid & 255, half = tid >> 8;
        float s = 0.f;
        for (int sl = half * 32; sl < half * 32 + 32; sl++) s += stats[sl * 256 + col];
        yt[tid] = s;
    }
    __syncthreads();
    if (tid < 128) {
        float S = yt[tid] + yt[256 + tid];
        float Q = yt[128 + tid] + yt[384 + tid];
        float mean = S * (1.0f / NN);
        float var  = Q * (1.0f / NN) - mean * mean;
        float sc   = gamma[tid] * rsqrtf(var + BN_EPS);
        ssl[tid]       = sc;
        ssl[HCC + tid] = beta[tid] - mean * sc;
    }
    __syncthreads();

    // stage x tile: unpack bf16, BN-apply, repack to bf16 pairs
    for (int q4 = tid; q4 < nNodes * 16; q4 += 512) {   // uint4 = 8 channels
        int n = q4 >> 4, c8 = q4 & 15;
        uint4 xv = *(const uint4*)(xp + (size_t)(node0 + n) * 64 + c8 * 4);
        int c = c8 * 8;
        float4 sc0 = *(const float4*)&ssl[c];
        float4 sc1 = *(const float4*)&ssl[c + 4];
        float4 sh0 = *(const float4*)&ssl[HCC + c];
        float4 sh1 = *(const float4*)&ssl[HCC + c + 4];
        unsigned* dst = &xb2[n * X2S + c8 * 4];
        dst[0] = f2bf_pack(bf_lo(xv.x) * sc0.x + sh0.x, bf_hi(xv.x) * sc0.y + sh0.y);
        dst[1] = f2bf_pack(bf_lo(xv.y) * sc0.z + sh0.z, bf_hi(xv.y) * sc0.w + sh0.w);
        dst[2] = f2bf_pack(bf_lo(xv.z) * sc1.x + sh1.x, bf_hi(xv.z) * sc1.y + sh1.y);
        dst[3] = f2bf_pack(bf_lo(xv.w) * sc1.z + sh1.z, bf_hi(xv.w) * sc1.w + sh1.w);
    }
    __syncthreads();

    int lane = tid & 63;
    int wv = __builtin_amdgcn_readfirstlane(tid >> 6);  // 0..7, wave-uniform
    int n = lane;

    // ---- stage 1: y[n][j0..j0+3] (weights via scalar loads)
    {
        int j0 = wv * 4;
        const float* w1p = W1 + j0 * 128;
        float acc[4];
#pragma unroll
        for (int k = 0; k < 4; k++) acc[k] = b1[j0 + k];
        if (n < nNodes) {
            for (int cb = 0; cb < 128; cb += 4) {
                unsigned p0 = xb2[n * X2S + (cb >> 1)];
                unsigned p1 = xb2[n * X2S + (cb >> 1) + 1];
                float xv0 = bf_lo(p0), xv1 = bf_hi(p0);
                float xv2 = bf_lo(p1), xv3 = bf_hi(p1);
#pragma unroll
                for (int k = 0; k < 4; k++) {
                    float4 w = *(const float4*)&w1p[k * 128 + cb];
                    acc[k] += xv0 * w.x + xv1 * w.y + xv2 * w.z + xv3 * w.w;
                }
            }
#pragma unroll
            for (int k = 0; k < 4; k++) yt[n * YS + j0 + k] = fmaxf(acc[k], 0.f);
        }
    }
    __syncthreads();

    // ---- stage 2: 16 h-channels per wave; head hd = wv>>1, half hh = wv&1
    {
        int hd = wv >> 1, hh = wv & 1;
        int c0 = hd * 32 + hh * 16;               // global channel base
        const float* w2p = W2 + c0 * 32;
        const float* aSp = aS + c0;               // aS[hd][hh*16 + kk]
        const float* aDp = aD + c0;
        if (n < nNodes) {
            float yreg[32];
#pragma unroll
            for (int j = 0; j < 32; j++) yreg[j] = yt[n * YS + j];
            float sa = 0.f, da = 0.f;
            unsigned* hrow = h + (size_t)(node0 + n) * 64;
            for (int kb = 0; kb < 16; kb += 8) {
                float acck[8];
#pragma unroll
                for (int kk = 0; kk < 8; kk++) acck[kk] = 0.f;
#pragma unroll
                for (int j = 0; j < 32; j += 4) {
#pragma unroll
                    for (int kk = 0; kk < 8; kk++) {
                        float4 w = *(const float4*)&w2p[(kb + kk) * 32 + j];
                        acck[kk] += yreg[j] * w.x + yreg[j + 1] * w.y +
                                    yreg[j + 2] * w.z + yreg[j + 3] * w.w;
                    }
                }
#pragma unroll
                for (int kk = 0; kk < 8; kk++) {
                    sa += acck[kk] * aSp[kb + kk];
                    da += acck[kk] * aDp[kb + kk];
                }
                uint4 pk;
                pk.x = f2bf_pack(acck[0], acck[1]);
                pk.y = f2bf_pack(acck[2], acck[3]);
                pk.z = f2bf_pack(acck[4], acck[5]);
                pk.w = f2bf_pack(acck[6], acck[7]);
                *(uint4*)(hrow + ((c0 + kb) >> 1)) = pk;
            }
            sdS[wv][n] = sa;
            sdD[wv][n] = da;
        }
    }
    __syncthreads();
    // combine the two half-head partial dots (even waves finalize)
    if ((wv & 1) == 0 && n < nNodes) {
        int hd = wv >> 1;
        asrc[(node0 + n) * 4 + hd] = sdS[wv][n] + sdS[wv + 1][n];
        adst[(node0 + n) * 4 + hd] = sdD[wv][n] + sdD[wv + 1][n];
    }
}

// -------- gather-aggregate: one 16-lane group per dst node; 4 nodes per wave.
// r12: exp-dedup — the 16 lanes of a group map onto the 16 (edge,head) pairs;
// each lane computes ONE exp + ONE asrc load, broadcast via __shfl
// (bit-identical values; removes 3 redundant exps + 3 loads per lane-iter).
// mode 1: write packed-bf16 x + BN stats. mode 2: fused mean-pool into gsum.
__global__ __launch_bounds__(256) void k_agg(const int* __restrict__ rowptr,
                                             const int* __restrict__ e_src,
                                             const float* __restrict__ asrc,
                                             const float* __restrict__ adst,
                                             const unsigned* __restrict__ h, // [N,64]
                                             const float* __restrict__ gat_b,
                                             unsigned* __restrict__ xo,      // [N,64]
                                             float* __restrict__ stats,      // [64][256]
                                             const int* __restrict__ batch,
                                             float* __restrict__ gsum,       // [G,128]
                                             int mode) {
    int tid = threadIdx.x, lane = tid & 63, wv = tid >> 6;
    int g  = lane >> 4;        // node group 0..3
    int li = lane & 15;        // lane within group: channels 8li..8li+7
    int hd = li >> 2;          // head of this channel block
    int te = li & 3;           // edge slot this lane owns the exp for
    int d  = blockIdx.x * 16 + wv * 4 + g;     // grid is exactly NN/16
    int gbase = lane & 48;     // first lane of this 16-lane group (within wave)

    float4 bA = *(const float4*)(gat_b + li * 8);
    float4 bB = *(const float4*)(gat_b + li * 8 + 4);

    int begin = rowptr[d];
    int end   = rowptr[d + 1];
    float adv = adst[d * 4 + hd];
    float asl = asrc[d * 4 + hd];
    uint4 hs  = *(const uint4*)(h + (size_t)d * 64 + li * 4);

    f32x2 acc0 = {0.f, 0.f}, acc1 = {0.f, 0.f}, acc2 = {0.f, 0.f}, acc3 = {0.f, 0.f};
    float ws = 0.f;

    int s[4];
    if (begin < end) {
#pragma unroll
        for (int t = 0; t < 4; t++) s[t] = e_src[min(begin + t, end - 1)];
    }

    for (int j = begin; j < end; j += 4) {
        uint4 hv[4];
#pragma unroll
        for (int t = 0; t < 4; t++) hv[t] = *(const uint4*)(h + (size_t)s[t] * 64 + li * 4);
        // this lane's exp: edge te, head hd (covers all 16 (t,hd) pairs/group)
        float avme = asrc[s[te] * 4 + hd];
        // prefetch next indices (independent of current gathers)
        int jn = j + 4;
        int sn[4];
#pragma unroll
        for (int t = 0; t < 4; t++) sn[t] = s[t];
        if (jn < end) {
#pragma unroll
            for (int t = 0; t < 4; t++) sn[t] = e_src[min(jn + t, end - 1)];
        }
        float lme = avme + adv; lme = lme > 0.f ? lme : 0.2f * lme;
        float wme = __expf(lme);
#pragma unroll
        for (int t = 0; t < 4; t++) {
            float wt = __shfl(wme, gbase + (hd << 2) + t, 64);
            float w = (j + t < end) ? wt : 0.f;
            f32x2 w2; w2.x = w; w2.y = w;
            acc0 += w2 * bfpair(hv[t].x);
            acc1 += w2 * bfpair(hv[t].y);
            acc2 += w2 * bfpair(hv[t].z);
            acc3 += w2 * bfpair(hv[t].w);
            ws += w;
        }
#pragma unroll
        for (int t = 0; t < 4; t++) s[t] = sn[t];
    }

    // self loop
    {
        float l = asl + adv; l = l > 0.f ? l : 0.2f * l;
        float w = __expf(l);
        f32x2 w2; w2.x = w; w2.y = w;
        acc0 += w2 * bfpair(hs.x);
        acc1 += w2 * bfpair(hs.y);
        acc2 += w2 * bfpair(hs.z);
        acc3 += w2 * bfpair(hs.w);
        ws += w;
    }

    float inv = 1.0f / (ws + 1e-16f);
    float o[8];
    o[0] = acc0.x * inv + bA.x; o[1] = acc0.y * inv + bA.y;
    o[2] = acc1.x * inv + bA.z; o[3] = acc1.y * inv + bA.w;
    o[4] = acc2.x * inv + bB.x; o[5] = acc2.y * inv + bB.y;
    o[6] = acc3.x * inv + bB.z; o[7] = acc3.y * inv + bB.w;

    __shared__ float redS[16 * 128], redQ[16 * 128];
    __shared__ int bg[16];
    int r = wv * 4 + g;

    if (mode == 1) {
        // packed-bf16 x write (16B per lane, 256B contiguous per node)
        uint4 pk;
        pk.x = f2bf_pack(o[0], o[1]);
        pk.y = f2bf_pack(o[2], o[3]);
        pk.z = f2bf_pack(o[4], o[5]);
        pk.w = f2bf_pack(o[6], o[7]);
        *(uint4*)(xo + (size_t)d * 64 + li * 4) = pk;

#pragma unroll
        for (int k = 0; k < 8; k++) {
            redS[r * 128 + li * 8 + k] = o[k];
            redQ[r * 128 + li * 8 + k] = o[k] * o[k];
        }
        __syncthreads();
        int slot = blockIdx.x & (NSLOT - 1);
        if (tid < 128) {
            float v = 0.f;
#pragma unroll
            for (int rr = 0; rr < 16; rr++) v += redS[rr * 128 + tid];
            atomicAdd(&stats[slot * 256 + tid], v);
        } else {
            int c = tid - 128;
            float v = 0.f;
#pragma unroll
            for (int rr = 0; rr < 16; rr++) v += redQ[rr * 128 + c];
            atomicAdd(&stats[slot * 256 + HCC + c], v);
        }
    } else {
        // fused mean-pool: accumulate o into gsum[batch[d]] (batch sorted)
        if (li == 0) bg[r] = batch[d];
#pragma unroll
        for (int k = 0; k < 8; k++) redS[r * 128 + li * 8 + k] = o[k];
        __syncthreads();
        if (tid < 128) {
            float sacc = 0.f;
            int curg = bg[0];
#pragma unroll
            for (int rr = 0; rr < 16; rr++) {
                int gg = bg[rr];
                if (gg != curg) {
                    atomicAdd(&gsum[curg * HCC + tid], sacc);
                    sacc = 0.f; curg = gg;
                }
                sacc += redS[rr * 128 + tid];
            }
            atomicAdd(&gsum[curg * HCC + tid], sacc);
        }
    }
}

// ------------- readout: out[g] = W·gsum[g] + cnt[g]·b  (tiny GEMV)
__global__ __launch_bounds__(128) void k_out(const float* __restrict__ gsum,
                                             const float* __restrict__ gcnt,
                                             const float* __restrict__ W,  // [10,128]
                                             const float* __restrict__ bb, // [10]
                                             float* __restrict__ out) {    // [G,10]
    __shared__ float v[128];
    int g = blockIdx.x, t = threadIdx.x;
    v[t] = gsum[g * HCC + t];
    __syncthreads();
    if (t < NOUT) {
        float acc = gcnt[g] * bb[t];
        const float* wr = W + t * HCC;
        for (int c = 0; c < HCC; c++) acc += v[c] * wr[c];
        out[g * NOUT + t] = acc;
    }
}

extern "C" void kernel_launch(void* const* d_in, const int* in_sizes, int n_in,
                              void* d_out, int out_size, void* d_ws, size_t ws_size,
                              hipStream_t stream) {
    const int*   x_idx = (const int*)d_in[0];
    const int*   ei    = (const int*)d_in[1];
    const int*   batch = (const int*)d_in[2];
    const float* embed = (const float*)d_in[3];
    const float* bn_g  = (const float*)d_in[4];
    const float* bn_b  = (const float*)d_in[5];
    const float* lin_W = (const float*)d_in[6];
    const float* lin_b = (const float*)d_in[7];
    const float* gat_W = (const float*)d_in[8];
    const float* att_s = (const float*)d_in[9];
    const float* att_d = (const float*)d_in[10];
    const float* gat_b = (const float*)d_in[11];
    const float* ro_W  = (const float*)d_in[12];
    const float* ro_b  = (const float*)d_in[13];
    float* out = (float*)d_out;

    // workspace layout (stats | gsum | gcnt | bkcnt contiguous -> single memset)
    const size_t STG = (size_t)NSLOT * 256;                // floats per stats stage
    unsigned* xp    = (unsigned*)d_ws;                     // [N,64] packed bf16
    unsigned* h     = xp + (size_t)NN * 64;                // [N,64] packed bf16
    float*    asrc  = (float*)(h + (size_t)NN * 64);       // [N,4]
    float*    adst  = asrc + (size_t)NN * NHD;             // [N,4]
    float*    stats = adst + (size_t)NN * NHD;             // [3][64][256]
    float*    gsum  = stats + 3 * STG;                     // [G,128]
    float*    gcnt  = gsum + (size_t)NG * HCC;             // [G]
    int*      bkcnt  = (int*)(gcnt + NG);                  // [NBUK] (memset 0)
    int*      bbase  = bkcnt + NBUK;                       // [NBUK]
    int*      bcnt   = bbase + NBUK;                       // [NBUK]
    int*      rowptr = bcnt + NBUK;                        // [N+1]
    unsigned* e_src  = (unsigned*)(rowptr + NN + 1);       // [E]

    hipMemsetAsync(stats, 0,
                   (3 * STG + (size_t)NG * HCC + NG) * sizeof(float) + NBUK * sizeof(int),
                   stream);

    k_pre<<<EMB_BLKS + (NE + EB - 1) / EB, 256, 0, stream>>>(x_idx, embed, xp, stats,
                                                             ei, bkcnt, batch, gcnt);
    k_bscan<<<1, 512, 0, stream>>>(bkcnt, bbase, bcnt, rowptr);
    k_bin<<<(NE + EB - 1) / EB, 256, 0, stream>>>(ei, bcnt, e_src);
    k_place<<<NBUK, 512, 0, stream>>>(bbase, e_src, rowptr);

    for (int l = 0; l < NL; ++l) {
        k_fused<<<(NN + 63) / 64, 512, 0, stream>>>(xp, stats + l * STG,
                                                    bn_g + l * HCC, bn_b + l * HCC,
                                                    lin_W + l * CC * HCC, lin_b + l * CC,
                                                    gat_W + l * HCC * CC,
                                                    att_s + l * NHD * CC,
                                                    att_d + l * NHD * CC,
                                                    h, asrc, adst);
        k_agg<<<NN / 16, 256, 0, stream>>>(rowptr, (const int*)e_src, asrc, adst, h,
                                           gat_b + l * HCC, xp,
                                           stats + (l + 1) * STG,
                                           batch, gsum,
                                           (l < NL - 1) ? 1 : 2);
    }

    k_out<<<NG, 128, 0, stream>>>(gsum, gcnt, ro_W, ro_b, out);
}

// Round 13
// 332.486 us; speedup vs baseline: 1.1198x; 1.1198x over previous
//
#include <hip/hip_runtime.h>

// Problem constants (match reference)
constexpr int NN   = 50000;          // nodes
constexpr int NE   = 800000;         // edges before self loops
constexpr int NHD  = 4;              // heads
constexpr int CC   = 32;             // channels per head
constexpr int HCC  = 128;            // NHD*CC
constexpr int NL   = 3;              // layers
constexpr int NG   = 128;            // graphs
constexpr int NOUT = 10;             // out channels
constexpr float BN_EPS = 1e-5f;

constexpr int X2S = 67;              // LDS x-row stride in packed uints (bank-safe)
constexpr int YS = 33;               // LDS y-row stride
constexpr int NSLOT = 64;            // stats slots (atomic-contention spreading)
constexpr int NBUK = (NN + 127) / 128;    // 391 dst buckets (128 dsts each)
constexpr int EB  = 2048;            // edges per hist/bin block (391 blocks)
constexpr int EMB_BLKS = 512;        // embed-part blocks in k_pre

// Session facts:
// r10: cooperative grid.sync mega-kernel 2.4x SLOWER (XCD L2 flush). Never retry.
// r12: k_fused 512-thread split REGRESSED (each wave re-reads full LDS row ->
//      2x LDS traffic). k_agg exp-dedup WON ~7us/layer. This file: r11 k_fused
//      (256t) + r12 k_agg (exp-dedup + packed fma) + merged k_pre.

typedef __attribute__((ext_vector_type(2))) float f32x2;

// fp32 -> bf16 (round-to-nearest-even), packed pair helpers
__device__ inline unsigned f2bf_pack(float a, float b) {
    unsigned ua = __float_as_uint(a); ua += 0x7FFFu + ((ua >> 16) & 1u);
    unsigned ub = __float_as_uint(b); ub += 0x7FFFu + ((ub >> 16) & 1u);
    return (ua >> 16) | (ub & 0xFFFF0000u);
}
__device__ inline float bf_lo(unsigned p) { return __uint_as_float(p << 16); }
__device__ inline float bf_hi(unsigned p) { return __uint_as_float(p & 0xFFFF0000u); }
__device__ inline f32x2 bfpair(unsigned p) {
    f32x2 r; r.x = __uint_as_float(p << 16); r.y = __uint_as_float(p & 0xFFFF0000u);
    return r;
}

// ------------- k_pre: embed gather + BN stats (blocks 0..511)  merged with
//               CSR bucket histogram + per-graph counts (blocks 512..902)
__global__ __launch_bounds__(256) void k_pre(const int* __restrict__ idx,
                                             const float* __restrict__ embed,
                                             unsigned* __restrict__ xp,   // [N,64]
                                             float* __restrict__ stats,   // [64][256]
                                             const int* __restrict__ ei,
                                             int* __restrict__ bkcnt,
                                             const int* __restrict__ batch,
                                             float* __restrict__ gcnt) {
    int tid = threadIdx.x;
    if (blockIdx.x < EMB_BLKS) {
        __shared__ float A[256], B[256], C[256], D[256];
        int i0 = blockIdx.x * 256 + tid;
        int stride = EMB_BLKS * 256;
        float s0 = 0.f, s1 = 0.f, q0 = 0.f, q1 = 0.f;
        for (int i = i0; i < NN * 64; i += stride) {  // packed uints: 2 ch each
            int n = i >> 6, c2 = (i & 63) << 1;
            float2 ev = *(const float2*)(embed + (size_t)idx[n] * HCC + c2);
            xp[i] = f2bf_pack(ev.x, ev.y);
            s0 += ev.x; q0 += ev.x * ev.x;
            s1 += ev.y; q1 += ev.y * ev.y;
        }
        A[tid] = s0; B[tid] = s1; C[tid] = q0; D[tid] = q1;
        __syncthreads();
        int slot = blockIdx.x & (NSLOT - 1);
        if (tid < 64) {
            int p = tid;                              // channel pair (2p, 2p+1)
            float S0 = A[p] + A[p + 64] + A[p + 128] + A[p + 192];
            float S1 = B[p] + B[p + 64] + B[p + 128] + B[p + 192];
            float Q0 = C[p] + C[p + 64] + C[p + 128] + C[p + 192];
            float Q1 = D[p] + D[p + 64] + D[p + 128] + D[p + 192];
            atomicAdd(&stats[slot * 256 + 2 * p],           S0);
            atomicAdd(&stats[slot * 256 + 2 * p + 1],       S1);
            atomicAdd(&stats[slot * 256 + HCC + 2 * p],     Q0);
            atomicAdd(&stats[slot * 256 + HCC + 2 * p + 1], Q1);
        }
    } else {
        __shared__ int hist[NBUK];
        __shared__ int lgc[NG];
        int b = blockIdx.x - EMB_BLKS;
        int e0 = b * EB, nE = min(EB, NE - e0);
        for (int i = tid; i < NBUK; i += 256) hist[i] = 0;
        for (int i = tid; i < NG; i += 256) lgc[i] = 0;
        __syncthreads();
        for (int i = tid; i < nE; i += 256)
            atomicAdd(&hist[ei[NE + e0 + i] >> 7], 1);
        int n0 = b * 128;
        if (tid < 128) {
            int n = n0 + tid;
            if (n < NN) atomicAdd(&lgc[batch[n]], 1);
        }
        __syncthreads();
        for (int i = tid; i < NBUK; i += 256)
            if (hist[i]) atomicAdd(&bkcnt[i], hist[i]);
        for (int i = tid; i < NG; i += 256)
            if (lgc[i]) atomicAdd(&gcnt[i], (float)lgc[i]);
    }
}

// -------- CSR build 2: parallel exclusive scan of 391 bucket totals
__global__ __launch_bounds__(512) void k_bscan(const int* __restrict__ bkcnt,
                                               int* __restrict__ bbase,
                                               int* __restrict__ bcnt,
                                               int* __restrict__ rowptr) {
    __shared__ int sc[512];
    int t = threadIdx.x;
    int v = (t < NBUK) ? bkcnt[t] : 0;
    sc[t] = v;
    __syncthreads();
#pragma unroll
    for (int off = 1; off < 512; off <<= 1) {
        int u = (t >= off) ? sc[t - off] : 0;
        __syncthreads();
        sc[t] += u;
        __syncthreads();
    }
    if (t < NBUK) {
        int excl = sc[t] - v;
        bbase[t] = excl;
        bcnt[t]  = excl;                          // atomic tail counters for k_bin
    }
    if (t == 0) rowptr[NN] = NE;
}

// -------- CSR build 3: LDS-aggregated bucket binning (range-reserved).
__global__ __launch_bounds__(256) void k_bin(const int* __restrict__ ei,
                                             int* __restrict__ bcnt,
                                             unsigned* __restrict__ e_src) {
    __shared__ int hist[NBUK], base[NBUK];
    int b = blockIdx.x, t = threadIdx.x;
    int e0 = b * EB;
    int nE = min(EB, NE - e0);

    for (int i = t; i < NBUK; i += 256) hist[i] = 0;
    __syncthreads();
    for (int i = t; i < nE; i += 256)
        atomicAdd(&hist[ei[NE + e0 + i] >> 7], 1);
    __syncthreads();
    for (int i = t; i < NBUK; i += 256) {
        int c = hist[i];
        if (c) base[i] = atomicAdd(&bcnt[i], c);
        hist[i] = 0;                              // reuse as placement offset
    }
    __syncthreads();
    for (int i = t; i < nE; i += 256) {
        int e = e0 + i;
        int d = ei[NE + e];
        int s = ei[e];
        int bk = d >> 7;
        int pos = base[bk] + atomicAdd(&hist[bk], 1);
        e_src[pos] = (unsigned)s | ((unsigned)(d & 127) << 17);
    }
}

// -------- CSR build 4: within-bucket placement; derives per-node rowptr.
__global__ __launch_bounds__(512) void k_place(const int* __restrict__ bbase,
                                               unsigned* __restrict__ e_src,
                                               int* __restrict__ rowptr) {
    __shared__ int lcnt[128], sc[128], lrp[128], cnt[128];
    int b = blockIdx.x, t = threadIdx.x;
    int d0 = b * 128;
    int rS = bbase[b];
    int rE = (b + 1 < NBUK) ? bbase[b + 1] : NE;
    int n = rE - rS;
    if (t < 128) { lcnt[t] = 0; cnt[t] = 0; }
    __syncthreads();
    unsigned pk[7];
#pragma unroll
    for (int k = 0; k < 7; k++) {
        int i = t + k * 512;
        if (i < n) {
            pk[k] = e_src[rS + i];
            atomicAdd(&lcnt[pk[k] >> 17], 1);
        }
    }
    __syncthreads();
    if (t < 128) sc[t] = lcnt[t];
    __syncthreads();
#pragma unroll
    for (int off = 1; off < 128; off <<= 1) {
        int u = (t < 128 && t >= off) ? sc[t - off] : 0;
        __syncthreads();
        if (t < 128) sc[t] += u;
        __syncthreads();
    }
    if (t < 128) {
        int start = rS + sc[t] - lcnt[t];
        lrp[t] = start;
        int d = d0 + t;
        if (d < NN) rowptr[d] = start;
    }
    __syncthreads();
#pragma unroll
    for (int k = 0; k < 7; k++) {
        int i = t + k * 512;
        if (i < n) {
            unsigned p = pk[k];
            int dl = p >> 17;
            int pos = lrp[dl] + atomicAdd(&cnt[dl], 1);
            e_src[pos] = p & 0x1FFFFu;
        }
    }
}

// ---------- fused BNfin + BN-apply + Linear+ReLU + GATw + att dots
// r11 verified version: 256 threads, BN-finalize across all 256 threads.
__global__ __launch_bounds__(256) void k_fused(const unsigned* __restrict__ xp,
                                               const float* __restrict__ stats, // [64][256]
                                               const float* __restrict__ gamma,
                                               const float* __restrict__ beta,
                                               const float* __restrict__ W1, // [32,128]
                                               const float* __restrict__ b1, // [32]
                                               const float* __restrict__ W2, // [128,32]
                                               const float* __restrict__ aS, // [4,32]
                                               const float* __restrict__ aD, // [4,32]
                                               unsigned* __restrict__ h,     // [N,64] packed
                                               float* __restrict__ asrc,     // [N,4]
                                               float* __restrict__ adst) {   // [N,4]
    __shared__ unsigned xb2[64 * X2S];            // 17152 B
    __shared__ float yt[64 * YS];                 //  8448 B
    __shared__ float __attribute__((aligned(16))) ssl[256];
    int tid = threadIdx.x;
    int node0 = blockIdx.x * 64;
    int nNodes = min(64, NN - node0);

    // BN finalize: all 256 threads sum one stats column each (yt as scratch)
    {
        float s = 0.f;
        for (int sl = 0; sl < NSLOT; sl++) s += stats[sl * 256 + tid];
        yt[tid] = s;
    }
    __syncthreads();
    if (tid < 128) {
        float S = yt[tid], Q = yt[128 + tid];
        float mean = S * (1.0f / NN);
        float var  = Q * (1.0f / NN) - mean * mean;
        float sc   = gamma[tid] * rsqrtf(var + BN_EPS);
        ssl[tid]       = sc;
        ssl[HCC + tid] = beta[tid] - mean * sc;
    }
    __syncthreads();

    // stage x tile: unpack bf16, BN-apply, repack to bf16 pairs
    {
        for (int q4 = tid; q4 < nNodes * 16; q4 += 256) {   // uint4 = 8 channels
            int n = q4 >> 4, c8 = q4 & 15;
            uint4 xv = *(const uint4*)(xp + (size_t)(node0 + n) * 64 + c8 * 4);
            int c = c8 * 8;
            float4 sc0 = *(const float4*)&ssl[c];
            float4 sc1 = *(const float4*)&ssl[c + 4];
            float4 sh0 = *(const float4*)&ssl[HCC + c];
            float4 sh1 = *(const float4*)&ssl[HCC + c + 4];
            unsigned* dst = &xb2[n * X2S + c8 * 4];
            dst[0] = f2bf_pack(bf_lo(xv.x) * sc0.x + sh0.x, bf_hi(xv.x) * sc0.y + sh0.y);
            dst[1] = f2bf_pack(bf_lo(xv.y) * sc0.z + sh0.z, bf_hi(xv.y) * sc0.w + sh0.w);
            dst[2] = f2bf_pack(bf_lo(xv.z) * sc1.x + sh1.x, bf_hi(xv.z) * sc1.y + sh1.y);
            dst[3] = f2bf_pack(bf_lo(xv.w) * sc1.z + sh1.z, bf_hi(xv.w) * sc1.w + sh1.w);
        }
    }
    __syncthreads();

    int lane = tid & 63;
    int wv = __builtin_amdgcn_readfirstlane(tid >> 6);
    int n = lane;

    // ---- stage 1: y[n][j0..j0+7] (weights via scalar loads)
    {
        int j0 = wv * 8;
        const float* w1p = W1 + j0 * 128;
        float acc[8];
#pragma unroll
        for (int k = 0; k < 8; k++) acc[k] = b1[j0 + k];
        if (n < nNodes) {
            for (int cb = 0; cb < 128; cb += 4) {
                unsigned p0 = xb2[n * X2S + (cb >> 1)];
                unsigned p1 = xb2[n * X2S + (cb >> 1) + 1];
                float xv0 = bf_lo(p0), xv1 = bf_hi(p0);
                float xv2 = bf_lo(p1), xv3 = bf_hi(p1);
#pragma unroll
                for (int k = 0; k < 8; k++) {
                    float4 w = *(const float4*)&w1p[k * 128 + cb];
                    acc[k] += xv0 * w.x + xv1 * w.y + xv2 * w.z + xv3 * w.w;
                }
            }
#pragma unroll
            for (int k = 0; k < 8; k++) yt[n * YS + j0 + k] = fmaxf(acc[k], 0.f);
        }
    }
    __syncthreads();

    // ---- stage 2: h[n][k0..k0+31] (bf16), head hd = wv
    if (n < nNodes) {
        int k0 = wv * 32, hd = wv;
        const float* w2p = W2 + k0 * 32;
        const float* aSp = aS + hd * 32;
        const float* aDp = aD + hd * 32;
        float yreg[32];
#pragma unroll
        for (int j = 0; j < 32; j++) yreg[j] = yt[n * YS + j];
        float sa = 0.f, da = 0.f;
        unsigned* hrow = h + (size_t)(node0 + n) * 64;
        for (int kb = 0; kb < 32; kb += 8) {
            float acck[8];
#pragma unroll
            for (int kk = 0; kk < 8; kk++) acck[kk] = 0.f;
#pragma unroll
            for (int j = 0; j < 32; j += 4) {
#pragma unroll
                for (int kk = 0; kk < 8; kk++) {
                    float4 w = *(const float4*)&w2p[(kb + kk) * 32 + j];
                    acck[kk] += yreg[j] * w.x + yreg[j + 1] * w.y +
                                yreg[j + 2] * w.z + yreg[j + 3] * w.w;
                }
            }
#pragma unroll
            for (int kk = 0; kk < 8; kk++) {
                sa += acck[kk] * aSp[kb + kk];
                da += acck[kk] * aDp[kb + kk];
            }
            uint4 pk;
            pk.x = f2bf_pack(acck[0], acck[1]);
            pk.y = f2bf_pack(acck[2], acck[3]);
            pk.z = f2bf_pack(acck[4], acck[5]);
            pk.w = f2bf_pack(acck[6], acck[7]);
            *(uint4*)(hrow + ((kb) >> 1) + (k0 >> 1)) = pk;
        }
        asrc[(node0 + n) * 4 + hd] = sa;
        adst[(node0 + n) * 4 + hd] = da;
    }
}

// -------- gather-aggregate: one 16-lane group per dst node; 4 nodes per wave.
// r12-verified exp-dedup: 16 lanes of a group map onto the 16 (edge,head)
// pairs; each lane computes ONE exp + ONE asrc load, broadcast via __shfl
// (bit-identical; −7us/layer measured). Packed-f32x2 accumulate.
// mode 1: write packed-bf16 x + BN stats. mode 2: fused mean-pool into gsum.
__global__ __launch_bounds__(256) void k_agg(const int* __restrict__ rowptr,
                                             const int* __restrict__ e_src,
                                             const float* __restrict__ asrc,
                                             const float* __restrict__ adst,
                                             const unsigned* __restrict__ h, // [N,64]
                                             const float* __restrict__ gat_b,
                                             unsigned* __restrict__ xo,      // [N,64]
                                             float* __restrict__ stats,      // [64][256]
                                             const int* __restrict__ batch,
                                             float* __restrict__ gsum,       // [G,128]
                                             int mode) {
    int tid = threadIdx.x, lane = tid & 63, wv = tid >> 6;
    int g  = lane >> 4;        // node group 0..3
    int li = lane & 15;        // lane within group: channels 8li..8li+7
    int hd = li >> 2;          // head of this channel block
    int te = li & 3;           // edge slot this lane owns the exp for
    int d  = blockIdx.x * 16 + wv * 4 + g;     // grid is exactly NN/16
    int gbase = lane & 48;     // first lane of this 16-lane group (within wave)

    float4 bA = *(const float4*)(gat_b + li * 8);
    float4 bB = *(const float4*)(gat_b + li * 8 + 4);

    int begin = rowptr[d];
    int end   = rowptr[d + 1];
    float adv = adst[d * 4 + hd];
    float asl = asrc[d * 4 + hd];
    uint4 hs  = *(const uint4*)(h + (size_t)d * 64 + li * 4);

    f32x2 acc0 = {0.f, 0.f}, acc1 = {0.f, 0.f}, acc2 = {0.f, 0.f}, acc3 = {0.f, 0.f};
    float ws = 0.f;

    int s[4];
    if (begin < end) {
#pragma unroll
        for (int t = 0; t < 4; t++) s[t] = e_src[min(begin + t, end - 1)];
    }

    for (int j = begin; j < end; j += 4) {
        uint4 hv[4];
#pragma unroll
        for (int t = 0; t < 4; t++) hv[t] = *(const uint4*)(h + (size_t)s[t] * 64 + li * 4);
        // this lane's exp: edge te, head hd (covers all 16 (t,hd) pairs/group)
        float avme = asrc[s[te] * 4 + hd];
        // prefetch next indices (independent of current gathers)
        int jn = j + 4;
        int sn[4];
#pragma unroll
        for (int t = 0; t < 4; t++) sn[t] = s[t];
        if (jn < end) {
#pragma unroll
            for (int t = 0; t < 4; t++) sn[t] = e_src[min(jn + t, end - 1)];
        }
        float lme = avme + adv; lme = lme > 0.f ? lme : 0.2f * lme;
        float wme = __expf(lme);
#pragma unroll
        for (int t = 0; t < 4; t++) {
            float wt = __shfl(wme, gbase + (hd << 2) + t, 64);
            float w = (j + t < end) ? wt : 0.f;
            f32x2 w2; w2.x = w; w2.y = w;
            acc0 += w2 * bfpair(hv[t].x);
            acc1 += w2 * bfpair(hv[t].y);
            acc2 += w2 * bfpair(hv[t].z);
            acc3 += w2 * bfpair(hv[t].w);
            ws += w;
        }
#pragma unroll
        for (int t = 0; t < 4; t++) s[t] = sn[t];
    }

    // self loop
    {
        float l = asl + adv; l = l > 0.f ? l : 0.2f * l;
        float w = __expf(l);
        f32x2 w2; w2.x = w; w2.y = w;
        acc0 += w2 * bfpair(hs.x);
        acc1 += w2 * bfpair(hs.y);
        acc2 += w2 * bfpair(hs.z);
        acc3 += w2 * bfpair(hs.w);
        ws += w;
    }

    float inv = 1.0f / (ws + 1e-16f);
    float o[8];
    o[0] = acc0.x * inv + bA.x; o[1] = acc0.y * inv + bA.y;
    o[2] = acc1.x * inv + bA.z; o[3] = acc1.y * inv + bA.w;
    o[4] = acc2.x * inv + bB.x; o[5] = acc2.y * inv + bB.y;
    o[6] = acc3.x * inv + bB.z; o[7] = acc3.y * inv + bB.w;

    __shared__ float redS[16 * 128], redQ[16 * 128];
    __shared__ int bg[16];
    int r = wv * 4 + g;

    if (mode == 1) {
        // packed-bf16 x write (16B per lane, 256B contiguous per node)
        uint4 pk;
        pk.x = f2bf_pack(o[0], o[1]);
        pk.y = f2bf_pack(o[2], o[3]);
        pk.z = f2bf_pack(o[4], o[5]);
        pk.w = f2bf_pack(o[6], o[7]);
        *(uint4*)(xo + (size_t)d * 64 + li * 4) = pk;

#pragma unroll
        for (int k = 0; k < 8; k++) {
            redS[r * 128 + li * 8 + k] = o[k];
            redQ[r * 128 + li * 8 + k] = o[k] * o[k];
        }
        __syncthreads();
        int slot = blockIdx.x & (NSLOT - 1);
        if (tid < 128) {
            float v = 0.f;
#pragma unroll
            for (int rr = 0; rr < 16; rr++) v += redS[rr * 128 + tid];
            atomicAdd(&stats[slot * 256 + tid], v);
        } else {
            int c = tid - 128;
            float v = 0.f;
#pragma unroll
            for (int rr = 0; rr < 16; rr++) v += redQ[rr * 128 + c];
            atomicAdd(&stats[slot * 256 + HCC + c], v);
        }
    } else {
        // fused mean-pool: accumulate o into gsum[batch[d]] (batch sorted)
        if (li == 0) bg[r] = batch[d];
#pragma unroll
        for (int k = 0; k < 8; k++) redS[r * 128 + li * 8 + k] = o[k];
        __syncthreads();
        if (tid < 128) {
            float sacc = 0.f;
            int curg = bg[0];
#pragma unroll
            for (int rr = 0; rr < 16; rr++) {
                int gg = bg[rr];
                if (gg != curg) {
                    atomicAdd(&gsum[curg * HCC + tid], sacc);
                    sacc = 0.f; curg = gg;
                }
                sacc += redS[rr * 128 + tid];
            }
            atomicAdd(&gsum[curg * HCC + tid], sacc);
        }
    }
}

// ------------- readout: out[g] = W·gsum[g] + cnt[g]·b  (tiny GEMV)
__global__ __launch_bounds__(128) void k_out(const float* __restrict__ gsum,
                                             const float* __restrict__ gcnt,
                                             const float* __restrict__ W,  // [10,128]
                                             const float* __restrict__ bb, // [10]
                                             float* __restrict__ out) {    // [G,10]
    __shared__ float v[128];
    int g = blockIdx.x, t = threadIdx.x;
    v[t] = gsum[g * HCC + t];
    __syncthreads();
    if (t < NOUT) {
        float acc = gcnt[g] * bb[t];
        const float* wr = W + t * HCC;
        for (int c = 0; c < HCC; c++) acc += v[c] * wr[c];
        out[g * NOUT + t] = acc;
    }
}

extern "C" void kernel_launch(void* const* d_in, const int* in_sizes, int n_in,
                              void* d_out, int out_size, void* d_ws, size_t ws_size,
                              hipStream_t stream) {
    const int*   x_idx = (const int*)d_in[0];
    const int*   ei    = (const int*)d_in[1];
    const int*   batch = (const int*)d_in[2];
    const float* embed = (const float*)d_in[3];
    const float* bn_g  = (const float*)d_in[4];
    const float* bn_b  = (const float*)d_in[5];
    const float* lin_W = (const float*)d_in[6];
    const float* lin_b = (const float*)d_in[7];
    const float* gat_W = (const float*)d_in[8];
    const float* att_s = (const float*)d_in[9];
    const float* att_d = (const float*)d_in[10];
    const float* gat_b = (const float*)d_in[11];
    const float* ro_W  = (const float*)d_in[12];
    const float* ro_b  = (const float*)d_in[13];
    float* out = (float*)d_out;

    // workspace layout (stats | gsum | gcnt | bkcnt contiguous -> single memset)
    const size_t STG = (size_t)NSLOT * 256;                // floats per stats stage
    unsigned* xp    = (unsigned*)d_ws;                     // [N,64] packed bf16
    unsigned* h     = xp + (size_t)NN * 64;                // [N,64] packed bf16
    float*    asrc  = (float*)(h + (size_t)NN * 64);       // [N,4]
    float*    adst  = asrc + (size_t)NN * NHD;             // [N,4]
    float*    stats = adst + (size_t)NN * NHD;             // [3][64][256]
    float*    gsum  = stats + 3 * STG;                     // [G,128]
    float*    gcnt  = gsum + (size_t)NG * HCC;             // [G]
    int*      bkcnt  = (int*)(gcnt + NG);                  // [NBUK] (memset 0)
    int*      bbase  = bkcnt + NBUK;                       // [NBUK]
    int*      bcnt   = bbase + NBUK;                       // [NBUK]
    int*      rowptr = bcnt + NBUK;                        // [N+1]
    unsigned* e_src  = (unsigned*)(rowptr + NN + 1);       // [E]

    hipMemsetAsync(stats, 0,
                   (3 * STG + (size_t)NG * HCC + NG) * sizeof(float) + NBUK * sizeof(int),
                   stream);

    k_pre<<<EMB_BLKS + (NE + EB - 1) / EB, 256, 0, stream>>>(x_idx, embed, xp, stats,
                                                             ei, bkcnt, batch, gcnt);
    k_bscan<<<1, 512, 0, stream>>>(bkcnt, bbase, bcnt, rowptr);
    k_bin<<<(NE + EB - 1) / EB, 256, 0, stream>>>(ei, bcnt, e_src);
    k_place<<<NBUK, 512, 0, stream>>>(bbase, e_src, rowptr);

    for (int l = 0; l < NL; ++l) {
        k_fused<<<(NN + 63) / 64, 256, 0, stream>>>(xp, stats + l * STG,
                                                    bn_g + l * HCC, bn_b + l * HCC,
                                                    lin_W + l * CC * HCC, lin_b + l * CC,
                                                    gat_W + l * HCC * CC,
                                                    att_s + l * NHD * CC,
                                                    att_d + l * NHD * CC,
                                                    h, asrc, adst);
        k_agg<<<NN / 16, 256, 0, stream>>>(rowptr, (const int*)e_src, asrc, adst, h,
                                           gat_b + l * HCC, xp,
                                           stats + (l + 1) * STG,
                                           batch, gsum,
                                           (l < NL - 1) ? 1 : 2);
    }

    k_out<<<NG, 128, 0, stream>>>(gsum, gcnt, ro_W, ro_b, out);
}